// Round 1
// baseline (6297.223 us; speedup 1.0000x reference)
//
#include <hip/hip_runtime.h>
#include <math.h>

#define MP 33
#define MSZ (32 * MP)          // 1056 floats per padded 32x32 matrix
#define NMAT 32768
#define SW_BATCH 8
#define SW_SINGLE 10

// workspace float offsets
#define WS_G    0
#define WS_GS   1024
#define WS_GIS  2048
#define WS_GT   3072
#define WS_GH   4096
#define WS_C    5120
#define WS_VAR  6144
#define WS_TOTAL 6400

// ---------------------------------------------------------------------------
// One-sided (Hestenes) Jacobi on a 32x32 SPD matrix; each lane of a 32-lane
// group owns one column in registers. Round-robin tournament ordering.
// After SW_BATCH sweeps, columns are (scaled) eigenvectors: w_k = u_k * sigma_k.
// ---------------------------------------------------------------------------
__device__ __forceinline__ void jacobi_onesided(float (&w)[32], int lane) {
    const int col  = lane & 31;
    const int base = lane & 32;
    for (int sweep = 0; sweep < SW_BATCH; ++sweep) {
        for (int r = 0; r < 31; ++r) {
            int part = (col == 31) ? r : ((col == r) ? 31 : ((2 * r - col + 62) % 31));
            int plane = base | part;
            float o[32];
            #pragma unroll
            for (int i = 0; i < 32; ++i) o[i] = __shfl(w[i], plane, 64);
            float down = 0.f, apq = 0.f;
            #pragma unroll
            for (int i = 0; i < 32; ++i) { down += w[i] * w[i]; apq += w[i] * o[i]; }
            float dpart = __shfl(down, plane, 64);
            bool isp = (col < part);
            float app = isp ? down : dpart;
            float aqq = isp ? dpart : down;
            float c = 1.f, sn = 0.f;
            if (fabsf(apq) > 1e-35f) {
                float th = (aqq - app) / (2.f * apq);
                float t  = copysignf(1.f, th) / (fabsf(th) + sqrtf(1.f + th * th));
                c  = rsqrtf(1.f + t * t);
                sn = t * c;
            }
            #pragma unroll
            for (int i = 0; i < 32; ++i)
                w[i] = isp ? (c * w[i] - sn * o[i]) : (sn * o[i] + c * w[i]);
        }
    }
}

// ---------------------------------------------------------------------------
// Column col of M = H * X * H  (H symmetric, both in padded LDS).
// ---------------------------------------------------------------------------
__device__ __forceinline__ void congr_col(const float* Xm, const float* HL,
                                          int col, float (&w)[32]) {
    float h[32], t[32];
    #pragma unroll
    for (int k = 0; k < 32; ++k) h[k] = HL[col * MP + k];
    #pragma unroll
    for (int i = 0; i < 32; ++i) {
        float a = 0.f;
        #pragma unroll
        for (int k = 0; k < 32; ++k) a += Xm[i * MP + k] * h[k];
        t[i] = a;
    }
    #pragma unroll
    for (int i = 0; i < 32; ++i) {
        float a = 0.f;
        #pragma unroll
        for (int k = 0; k < 32; ++k) a += HL[i * MP + k] * t[k];
        w[i] = a;
    }
}

// ---------------------------------------------------------------------------
// Two-sided Jacobi (with eigenvector accumulation) on a single 32x32 symmetric
// matrix living in padded LDS. Block = 64 threads (one wave). Handles
// indefinite matrices (keeps eigenvalue signs). Eigenvalues end on diag(A).
// ---------------------------------------------------------------------------
__device__ void jacobi2s(float* A, float* V, int lane, int sweeps) {
    const int col = lane & 31;
    const int r0  = (lane >> 5) * 16;
    for (int ii = 0; ii < 16; ++ii) V[(r0 + ii) * MP + col] = ((r0 + ii) == col) ? 1.f : 0.f;
    __syncthreads();
    for (int sw = 0; sw < sweeps; ++sw) {
        for (int r = 0; r < 31; ++r) {
            int part = (col == 31) ? r : ((col == r) ? 31 : ((2 * r - col + 62) % 31));
            int p = col < part ? col : part;
            int q = col < part ? part : col;
            bool isp = (col == p);
            float app = A[p * MP + p], aqq = A[q * MP + q], apq = A[p * MP + q];
            float c = 1.f, sn = 0.f;
            if (fabsf(apq) > 1e-35f) {
                float th = (aqq - app) / (2.f * apq);
                float t  = copysignf(1.f, th) / (fabsf(th) + sqrtf(1.f + th * th));
                c  = rsqrtf(1.f + t * t);
                sn = t * c;
            }
            float tmp[16];
            // column phase: A <- A*J
            #pragma unroll
            for (int ii = 0; ii < 16; ++ii) {
                float xp = A[(r0 + ii) * MP + p], xq = A[(r0 + ii) * MP + q];
                tmp[ii] = isp ? (c * xp - sn * xq) : (sn * xp + c * xq);
            }
            __syncthreads();
            #pragma unroll
            for (int ii = 0; ii < 16; ++ii) A[(r0 + ii) * MP + col] = tmp[ii];
            __syncthreads();
            // row phase: A <- J^T*A
            #pragma unroll
            for (int ii = 0; ii < 16; ++ii) {
                float rp = A[p * MP + (r0 + ii)], rq = A[q * MP + (r0 + ii)];
                tmp[ii] = isp ? (c * rp - sn * rq) : (sn * rp + c * rq);
            }
            __syncthreads();
            #pragma unroll
            for (int ii = 0; ii < 16; ++ii) A[col * MP + (r0 + ii)] = tmp[ii];
            __syncthreads();
            // V <- V*J
            #pragma unroll
            for (int ii = 0; ii < 16; ++ii) {
                float xp = V[(r0 + ii) * MP + p], xq = V[(r0 + ii) * MP + q];
                tmp[ii] = isp ? (c * xp - sn * xq) : (sn * xp + c * xq);
            }
            __syncthreads();
            #pragma unroll
            for (int ii = 0; ii < 16; ++ii) V[(r0 + ii) * MP + col] = tmp[ii];
            __syncthreads();
        }
    }
}

// O[i][j] = sum_k V[i][k] * f(lam_k) * V[j][k];  mode 0: sqrt, 1: rsqrt, 2: exp
__device__ void recon_f(const float* A, const float* V, float* O, int lane, int mode) {
    const int col = lane & 31;
    const int r0  = (lane >> 5) * 16;
    float fv[32];
    #pragma unroll
    for (int k = 0; k < 32; ++k) {
        float lam = A[k * MP + k];
        float f = (mode == 0) ? sqrtf(lam) : (mode == 1) ? rsqrtf(lam) : expf(lam);
        fv[k] = f * V[col * MP + k];
    }
    __syncthreads();
    for (int i = r0; i < r0 + 16; ++i) {
        float a = 0.f;
        #pragma unroll
        for (int k = 0; k < 32; ++k) a += V[i * MP + k] * fv[k];
        O[i * MP + col] = a;
    }
    __syncthreads();
}

// O = P * Q (padded LDS, distinct buffers)
__device__ void mmul(const float* P, const float* Q, float* O, int lane) {
    const int col = lane & 31;
    const int r0  = (lane >> 5) * 16;
    for (int i = r0; i < r0 + 16; ++i) {
        float a = 0.f;
        #pragma unroll
        for (int k = 0; k < 32; ++k) a += P[i * MP + k] * Q[k * MP + col];
        O[i * MP + col] = a;
    }
    __syncthreads();
}

// ---------------------------------------------------------------------------
// K1: arithmetic mean of 32768 matrices -> ws[WS_G]
// ---------------------------------------------------------------------------
__global__ __launch_bounds__(256) void k_mean(const float* __restrict__ X,
                                              float* __restrict__ ws) {
    const int t = threadIdx.x;
    const size_t base = (size_t)blockIdx.x * 64 * 1024;
    float a0 = 0.f, a1 = 0.f, a2 = 0.f, a3 = 0.f;
    for (int m = 0; m < 64; ++m) {
        const float* p = X + base + (size_t)m * 1024;
        a0 += p[t];
        a1 += p[t + 256];
        a2 += p[t + 512];
        a3 += p[t + 768];
    }
    const float s = 1.0f / (float)NMAT;
    atomicAdd(ws + WS_G + t,       a0 * s);
    atomicAdd(ws + WS_G + 256 + t, a1 * s);
    atomicAdd(ws + WS_G + 512 + t, a2 * s);
    atomicAdd(ws + WS_G + 768 + t, a3 * s);
}

// ---------------------------------------------------------------------------
// K2: block 0: eig(G) -> Gs = G^{1/2}, Gis = G^{-1/2}
//     block 1: eig(B) -> Bs = B^{1/2};  C = Bs * R
// ---------------------------------------------------------------------------
__global__ __launch_bounds__(64) void k_small_prep(const float* __restrict__ R,
                                                   const float* __restrict__ B,
                                                   float* __restrict__ ws) {
    __shared__ float A[MSZ], V[MSZ], T1[MSZ], T2[MSZ];
    const int lane = threadIdx.x;
    if (blockIdx.x == 0) {
        for (int e = lane; e < 1024; e += 64) A[(e >> 5) * MP + (e & 31)] = ws[WS_G + e];
        __syncthreads();
        jacobi2s(A, V, lane, SW_SINGLE);
        recon_f(A, V, T1, lane, 0);   // Gs
        recon_f(A, V, T2, lane, 1);   // Gis
        for (int e = lane; e < 1024; e += 64) {
            ws[WS_GS + e]  = T1[(e >> 5) * MP + (e & 31)];
            ws[WS_GIS + e] = T2[(e >> 5) * MP + (e & 31)];
        }
    } else {
        for (int e = lane; e < 1024; e += 64) A[(e >> 5) * MP + (e & 31)] = B[e];
        __syncthreads();
        jacobi2s(A, V, lane, SW_SINGLE);
        recon_f(A, V, T1, lane, 0);   // Bs = B^{1/2}
        for (int e = lane; e < 1024; e += 64) T2[(e >> 5) * MP + (e & 31)] = R[e];
        __syncthreads();
        mmul(T1, T2, V, lane);        // C = Bs * R (reuse V as output buffer)
        for (int e = lane; e < 1024; e += 64) ws[WS_C + e] = V[(e >> 5) * MP + (e & 31)];
    }
}

// ---------------------------------------------------------------------------
// K3: per matrix: M = Gis * X * Gis; one-sided Jacobi; accumulate
//     mean(log M) into ws[WS_GT] via LDS + global atomics.
// ---------------------------------------------------------------------------
__global__ __launch_bounds__(256) void k_batch_log(const float* __restrict__ X,
                                                   float* __restrict__ ws) {
    __shared__ float XL[8 * MSZ];
    __shared__ float HL[MSZ];
    __shared__ float ACC[MSZ];
    const int tid = threadIdx.x;
    for (int e = tid; e < 1024; e += 256) HL[(e >> 5) * MP + (e & 31)] = ws[WS_GIS + e];
    for (int e = tid; e < MSZ; e += 256) ACC[e] = 0.f;
    const size_t gbase = (size_t)blockIdx.x * 8192;
    for (int e = tid; e < 8192; e += 256) {
        int mat = e >> 10, idx = e & 1023;
        XL[mat * MSZ + (idx >> 5) * MP + (idx & 31)] = X[gbase + e];
    }
    __syncthreads();

    const int lane = tid & 63;
    const int wv   = tid >> 6;
    const int col  = lane & 31;
    const int matl = wv * 2 + (lane >> 5);
    float* Wm = XL + matl * MSZ;

    float w[32];
    congr_col(Wm, HL, col, w);       // w = column col of M = Gis X Gis
    jacobi_onesided(w, lane);

    float d2 = 0.f;
    #pragma unroll
    for (int i = 0; i < 32; ++i) d2 += w[i] * w[i];
    float g = 0.5f * logf(d2) / d2;  // log(sigma)/sigma^2

    // write W over the X tile (same wave only touches its own tile)
    #pragma unroll
    for (int i = 0; i < 32; ++i) Wm[i * MP + col] = w[i];
    float gr[32];
    #pragma unroll
    for (int k = 0; k < 32; ++k) {
        float gk = __shfl(g, (lane & 32) | k, 64);
        gr[k] = gk * Wm[col * MP + k];
    }
    const float invN = 1.0f / (float)NMAT;
    #pragma unroll
    for (int i = 0; i < 32; ++i) {
        float a = 0.f;
        #pragma unroll
        for (int k = 0; k < 32; ++k) a += Wm[i * MP + k] * gr[k];
        atomicAdd(&ACC[i * MP + col], a * invN);
    }
    __syncthreads();
    for (int e = tid; e < 1024; e += 256)
        atomicAdd(ws + WS_GT + e, ACC[(e >> 5) * MP + (e & 31)]);
}

// ---------------------------------------------------------------------------
// K4: E = exp(GT); Gn = Gs*E*Gs; Gh = Gn^{-1/2} -> ws[WS_GH]
// ---------------------------------------------------------------------------
__global__ __launch_bounds__(64) void k_karcher(float* __restrict__ ws) {
    __shared__ float A[MSZ], V[MSZ], E[MSZ], GS[MSZ], T[MSZ];
    const int lane = threadIdx.x;
    for (int e = lane; e < 1024; e += 64) {
        A[(e >> 5) * MP + (e & 31)]  = ws[WS_GT + e];
        GS[(e >> 5) * MP + (e & 31)] = ws[WS_GS + e];
    }
    __syncthreads();
    jacobi2s(A, V, lane, SW_SINGLE);
    recon_f(A, V, E, lane, 2);        // exp(GT) (handles indefinite GT)
    mmul(GS, E, T, lane);             // T = Gs*E
    mmul(T, GS, A, lane);             // A = Gn
    jacobi2s(A, V, lane, SW_SINGLE);
    recon_f(A, V, E, lane, 1);        // Gh = Gn^{-1/2}
    for (int e = lane; e < 1024; e += 64) ws[WS_GH + e] = E[(e >> 5) * MP + (e & 31)];
}

// ---------------------------------------------------------------------------
// K5: per matrix: Xw = Gh*X*Gh; Jacobi; var += sum(log(sigma)^2);
//     store W into d_out (scratch reuse).
// ---------------------------------------------------------------------------
__global__ __launch_bounds__(256) void k_batch_whiten(const float* __restrict__ X,
                                                      float* __restrict__ out,
                                                      float* __restrict__ ws) {
    __shared__ float XL[8 * MSZ];
    __shared__ float HL[MSZ];
    const int tid = threadIdx.x;
    for (int e = tid; e < 1024; e += 256) HL[(e >> 5) * MP + (e & 31)] = ws[WS_GH + e];
    const size_t gbase = (size_t)blockIdx.x * 8192;
    for (int e = tid; e < 8192; e += 256) {
        int mat = e >> 10, idx = e & 1023;
        XL[mat * MSZ + (idx >> 5) * MP + (idx & 31)] = X[gbase + e];
    }
    __syncthreads();

    const int lane = tid & 63;
    const int wv   = tid >> 6;
    const int col  = lane & 31;
    const int matl = wv * 2 + (lane >> 5);
    float* Wm = XL + matl * MSZ;

    float w[32];
    congr_col(Wm, HL, col, w);
    jacobi_onesided(w, lane);

    float d2 = 0.f;
    #pragma unroll
    for (int i = 0; i < 32; ++i) d2 += w[i] * w[i];
    float lg = 0.5f * logf(d2);
    float contrib = lg * lg;
    #pragma unroll
    for (int m = 16; m >= 1; m >>= 1) contrib += __shfl_xor(contrib, m, 64);
    if (col == 0) atomicAdd(ws + WS_VAR, contrib * (1.0f / (float)NMAT));

    const size_t gm = gbase / 1024 + matl;
    #pragma unroll
    for (int i = 0; i < 32; ++i) out[gm * 1024 + i * 32 + col] = w[i];
}

// ---------------------------------------------------------------------------
// K7: p = sqrt(1/(var+eps)); per matrix: Y = C*W*diag(sigma^{(p-2)/2});
//     Xo = Y*Y^T -> d_out.
// ---------------------------------------------------------------------------
__global__ __launch_bounds__(256) void k_final(float* __restrict__ out,
                                               const float* __restrict__ ws) {
    __shared__ float YL[8 * MSZ];
    __shared__ float CL[MSZ];
    const int tid = threadIdx.x;
    for (int e = tid; e < 1024; e += 256) CL[(e >> 5) * MP + (e & 31)] = ws[WS_C + e];
    const size_t gbase = (size_t)blockIdx.x * 8192;
    for (int e = tid; e < 8192; e += 256) {
        int mat = e >> 10, idx = e & 1023;
        YL[mat * MSZ + (idx >> 5) * MP + (idx & 31)] = out[gbase + e];
    }
    __syncthreads();

    const float var = ws[WS_VAR];
    const float p = sqrtf(1.0f / (var + 1e-5f));

    const int lane = tid & 63;
    const int wv   = tid >> 6;
    const int col  = lane & 31;
    const int matl = wv * 2 + (lane >> 5);
    float* Ym = YL + matl * MSZ;

    float w[32];
    #pragma unroll
    for (int i = 0; i < 32; ++i) w[i] = Ym[i * MP + col];
    float d2 = 0.f;
    #pragma unroll
    for (int i = 0; i < 32; ++i) d2 += w[i] * w[i];
    const float dj = exp2f(log2f(d2) * (p - 2.0f) * 0.25f);  // sigma^{(p-2)/2}

    float y[32];
    #pragma unroll
    for (int i = 0; i < 32; ++i) {
        float a = 0.f;
        #pragma unroll
        for (int k = 0; k < 32; ++k) a += CL[i * MP + k] * w[k];
        y[i] = a * dj;
    }
    #pragma unroll
    for (int i = 0; i < 32; ++i) Ym[i * MP + col] = y[i];

    float yr[32];
    #pragma unroll
    for (int k = 0; k < 32; ++k) yr[k] = Ym[col * MP + k];

    const size_t gm = gbase / 1024 + matl;
    #pragma unroll
    for (int i = 0; i < 32; ++i) {
        float a = 0.f;
        #pragma unroll
        for (int k = 0; k < 32; ++k) a += Ym[i * MP + k] * yr[k];
        out[gm * 1024 + i * 32 + col] = a;
    }
}

extern "C" void kernel_launch(void* const* d_in, const int* in_sizes, int n_in,
                              void* d_out, int out_size, void* d_ws, size_t ws_size,
                              hipStream_t stream) {
    const float* X = (const float*)d_in[0];
    const float* R = (const float*)d_in[1];
    const float* B = (const float*)d_in[2];
    float* out = (float*)d_out;
    float* ws  = (float*)d_ws;

    hipMemsetAsync(d_ws, 0, WS_TOTAL * sizeof(float), stream);
    k_mean<<<NMAT / 64, 256, 0, stream>>>(X, ws);
    k_small_prep<<<2, 64, 0, stream>>>(R, B, ws);
    k_batch_log<<<NMAT / 8, 256, 0, stream>>>(X, ws);
    k_karcher<<<1, 64, 0, stream>>>(ws);
    k_batch_whiten<<<NMAT / 8, 256, 0, stream>>>(X, out, ws);
    k_final<<<NMAT / 8, 256, 0, stream>>>(out, ws);
}

// Round 2
// 4077.607 us; speedup vs baseline: 1.5443x; 1.5443x over previous
//
#include <hip/hip_runtime.h>
#include <math.h>

typedef float v2f __attribute__((ext_vector_type(2)));

#define MP 33
#define MSZ (32 * MP)
#define NMAT 32768
#define SW1 6          // pass-1 sweeps (cold start)
#define SW2 4          // pass-2 sweeps (warm start)
#define SW_SINGLE 10

// workspace float offsets
#define WS_G    0
#define WS_GS   1024
#define WS_GIS  2048
#define WS_GT   3072
#define WS_K    4096
#define WS_C    5120
#define WS_VAR  6144
#define WS_TOTAL 6400

// pair-swizzled 32x32 tile: pair p (elements 2p,2p+1) of row r stored at
// float offset r*32 + 2*(p ^ (r&15)) (+ (c&1)). Conflict-free (<=2-way) for
// row-pair reads, column scalar writes/reads, and broadcast reads.
__device__ __forceinline__ int swz(int r, int c) {
    return r * 32 + 2 * ((c >> 1) ^ (r & 15)) + (c & 1);
}
__device__ __forceinline__ int swz2(int r, int p) {   // address of pair p of row r
    return r * 32 + 2 * (p ^ (r & 15));
}

// ---------------------------------------------------------------------------
// One-sided Jacobi, float2-packed columns, XOR tournament, incremental norms.
// 32-lane half-wave per matrix; lane owns column col (16 v2f regs).
// ---------------------------------------------------------------------------
__device__ __forceinline__ void jacobi_v2(v2f (&w2)[16], int col, int base, int sweeps) {
    #pragma unroll 1
    for (int sweep = 0; sweep < sweeps; ++sweep) {
        v2f na = {0.f, 0.f};
        #pragma unroll
        for (int j = 0; j < 16; ++j) na += w2[j] * w2[j];
        float dn = na.x + na.y;                       // fresh norm each sweep
        #pragma unroll 1
        for (int m = 1; m < 32; ++m) {
            const int part = col ^ m;
            const int plane = base | part;
            v2f o2[16];
            #pragma unroll
            for (int j = 0; j < 16; ++j) {
                o2[j].x = __shfl(w2[j].x, plane, 64);
                o2[j].y = __shfl(w2[j].y, plane, 64);
            }
            v2f ap2 = {0.f, 0.f};
            #pragma unroll
            for (int j = 0; j < 16; ++j) ap2 += w2[j] * o2[j];
            const float apq = ap2.x + ap2.y;
            const float dpart = __shfl(dn, plane, 64);
            const bool isp = col < part;
            const float app = isp ? dn : dpart;
            const float aqq = isp ? dpart : dn;
            float t = 0.f, c = 1.f, sn = 0.f;
            if (fabsf(apq) > 1e-30f) {
                const float th = (aqq - app) / (2.f * apq);
                t = copysignf(1.f, th) / (fabsf(th) + sqrtf(1.f + th * th));
                const float ci = rsqrtf(1.f + t * t);
                c = ci; sn = t * ci;
            }
            const float ss = isp ? -sn : sn;
            const v2f c2 = {c, c}, ss2 = {ss, ss};
            #pragma unroll
            for (int j = 0; j < 16; ++j) w2[j] = c2 * w2[j] + ss2 * o2[j];
            dn += (isp ? -t : t) * apq;               // app-=t*apq / aqq+=t*apq
        }
    }
}

// ---------------------------------------------------------------------------
// Two-sided Jacobi for the single small matrices (unchanged from round 1).
// ---------------------------------------------------------------------------
__device__ void jacobi2s(float* A, float* V, int lane, int sweeps) {
    const int col = lane & 31;
    const int r0  = (lane >> 5) * 16;
    for (int ii = 0; ii < 16; ++ii) V[(r0 + ii) * MP + col] = ((r0 + ii) == col) ? 1.f : 0.f;
    __syncthreads();
    for (int sw = 0; sw < sweeps; ++sw) {
        for (int r = 0; r < 31; ++r) {
            int part = (col == 31) ? r : ((col == r) ? 31 : ((2 * r - col + 62) % 31));
            int p = col < part ? col : part;
            int q = col < part ? part : col;
            bool isp = (col == p);
            float app = A[p * MP + p], aqq = A[q * MP + q], apq = A[p * MP + q];
            float c = 1.f, sn = 0.f;
            if (fabsf(apq) > 1e-35f) {
                float th = (aqq - app) / (2.f * apq);
                float t  = copysignf(1.f, th) / (fabsf(th) + sqrtf(1.f + th * th));
                c  = rsqrtf(1.f + t * t);
                sn = t * c;
            }
            float tmp[16];
            #pragma unroll
            for (int ii = 0; ii < 16; ++ii) {
                float xp = A[(r0 + ii) * MP + p], xq = A[(r0 + ii) * MP + q];
                tmp[ii] = isp ? (c * xp - sn * xq) : (sn * xp + c * xq);
            }
            __syncthreads();
            #pragma unroll
            for (int ii = 0; ii < 16; ++ii) A[(r0 + ii) * MP + col] = tmp[ii];
            __syncthreads();
            #pragma unroll
            for (int ii = 0; ii < 16; ++ii) {
                float rp = A[p * MP + (r0 + ii)], rq = A[q * MP + (r0 + ii)];
                tmp[ii] = isp ? (c * rp - sn * rq) : (sn * rp + c * rq);
            }
            __syncthreads();
            #pragma unroll
            for (int ii = 0; ii < 16; ++ii) A[col * MP + (r0 + ii)] = tmp[ii];
            __syncthreads();
            #pragma unroll
            for (int ii = 0; ii < 16; ++ii) {
                float xp = V[(r0 + ii) * MP + p], xq = V[(r0 + ii) * MP + q];
                tmp[ii] = isp ? (c * xp - sn * xq) : (sn * xp + c * xq);
            }
            __syncthreads();
            #pragma unroll
            for (int ii = 0; ii < 16; ++ii) V[(r0 + ii) * MP + col] = tmp[ii];
            __syncthreads();
        }
    }
}

__device__ void recon_f(const float* A, const float* V, float* O, int lane, int mode) {
    const int col = lane & 31;
    const int r0  = (lane >> 5) * 16;
    float fv[32];
    #pragma unroll
    for (int k = 0; k < 32; ++k) {
        float lam = A[k * MP + k];
        float f = (mode == 0) ? sqrtf(lam) : (mode == 1) ? rsqrtf(lam) : expf(lam);
        fv[k] = f * V[col * MP + k];
    }
    __syncthreads();
    for (int i = r0; i < r0 + 16; ++i) {
        float a = 0.f;
        #pragma unroll
        for (int k = 0; k < 32; ++k) a += V[i * MP + k] * fv[k];
        O[i * MP + col] = a;
    }
    __syncthreads();
}

__device__ void mmul(const float* P, const float* Q, float* O, int lane) {
    const int col = lane & 31;
    const int r0  = (lane >> 5) * 16;
    for (int i = r0; i < r0 + 16; ++i) {
        float a = 0.f;
        #pragma unroll
        for (int k = 0; k < 32; ++k) a += P[i * MP + k] * Q[k * MP + col];
        O[i * MP + col] = a;
    }
    __syncthreads();
}

// ---------------------------------------------------------------------------
// K1: arithmetic mean -> ws[WS_G]
// ---------------------------------------------------------------------------
__global__ __launch_bounds__(256) void k_mean(const float* __restrict__ X,
                                              float* __restrict__ ws) {
    const int t = threadIdx.x;
    const size_t base = (size_t)blockIdx.x * 64 * 1024;
    float a0 = 0.f, a1 = 0.f, a2 = 0.f, a3 = 0.f;
    for (int m = 0; m < 64; ++m) {
        const float* p = X + base + (size_t)m * 1024;
        a0 += p[t];
        a1 += p[t + 256];
        a2 += p[t + 512];
        a3 += p[t + 768];
    }
    const float s = 1.0f / (float)NMAT;
    atomicAdd(ws + WS_G + t,       a0 * s);
    atomicAdd(ws + WS_G + 256 + t, a1 * s);
    atomicAdd(ws + WS_G + 512 + t, a2 * s);
    atomicAdd(ws + WS_G + 768 + t, a3 * s);
}

// ---------------------------------------------------------------------------
// K2: block 0: eig(G) -> Gs, Gis.  block 1: eig(B) -> C = B^{1/2} R.
// ---------------------------------------------------------------------------
__global__ __launch_bounds__(64) void k_small_prep(const float* __restrict__ R,
                                                   const float* __restrict__ B,
                                                   float* __restrict__ ws) {
    __shared__ float A[MSZ], V[MSZ], T1[MSZ], T2[MSZ];
    const int lane = threadIdx.x;
    if (blockIdx.x == 0) {
        for (int e = lane; e < 1024; e += 64) A[(e >> 5) * MP + (e & 31)] = ws[WS_G + e];
        __syncthreads();
        jacobi2s(A, V, lane, SW_SINGLE);
        recon_f(A, V, T1, lane, 0);   // Gs
        recon_f(A, V, T2, lane, 1);   // Gis
        for (int e = lane; e < 1024; e += 64) {
            ws[WS_GS + e]  = T1[(e >> 5) * MP + (e & 31)];
            ws[WS_GIS + e] = T2[(e >> 5) * MP + (e & 31)];
        }
    } else {
        for (int e = lane; e < 1024; e += 64) A[(e >> 5) * MP + (e & 31)] = B[e];
        __syncthreads();
        jacobi2s(A, V, lane, SW_SINGLE);
        recon_f(A, V, T1, lane, 0);   // Bs
        for (int e = lane; e < 1024; e += 64) T2[(e >> 5) * MP + (e & 31)] = R[e];
        __syncthreads();
        mmul(T1, T2, V, lane);        // C = Bs * R
        for (int e = lane; e < 1024; e += 64) ws[WS_C + e] = V[(e >> 5) * MP + (e & 31)];
    }
}

// ---------------------------------------------------------------------------
// K3 (pass 1): M = Gis X Gis; Jacobi; GT += mean(log M); W1 -> w1out (d_out).
// ---------------------------------------------------------------------------
__global__ __launch_bounds__(256, 4) void k_batch_log(const float* __restrict__ X,
                                                      float* __restrict__ w1out,
                                                      float* __restrict__ ws) {
    __shared__ float XL[8 * 1024];   // pair-swizzled tiles
    __shared__ float HL[1024];       // Gis, pair-swizzled
    __shared__ float ACC[1024];      // natural layout
    const int tid = threadIdx.x;
    for (int e = tid; e < 1024; e += 256) {
        int r = e >> 5, c = e & 31;
        HL[swz(r, c)] = ws[WS_GIS + e];
        ACC[e] = 0.f;
    }
    const size_t gbase = (size_t)blockIdx.x * 8192;
    for (int e = tid; e < 8192; e += 256) {
        int mat = e >> 10, idx = e & 1023, r = idx >> 5, c = idx & 31;
        XL[mat * 1024 + swz(r, c)] = X[gbase + e];
    }
    __syncthreads();

    const int lane = tid & 63;
    const int base = lane & 32;
    const int col  = lane & 31;
    const int matl = (tid >> 6) * 2 + (lane >> 5);
    float* Xm = XL + matl * 1024;
    const int cm = col & 15, cbase = col * 32;

    // h2[p] = Gis[col, 2p..2p+1]
    v2f h2[16];
    #pragma unroll
    for (int p = 0; p < 16; ++p) h2[p] = *(const v2f*)&HL[cbase + 2 * (p ^ cm)];

    // t = X * h   (X rows broadcast from LDS)
    v2f t2[16];
    #pragma unroll
    for (int i = 0; i < 32; ++i) {
        v2f acc = {0.f, 0.f};
        #pragma unroll
        for (int s = 0; s < 16; ++s)
            acc += *(const v2f*)&Xm[i * 32 + 2 * s] * h2[s ^ (i & 15)];
        float ti = acc.x + acc.y;
        if (i & 1) t2[i >> 1].y = ti; else t2[i >> 1].x = ti;
    }
    // w = Gis * t
    v2f w2[16];
    #pragma unroll
    for (int i = 0; i < 32; ++i) {
        v2f acc = {0.f, 0.f};
        #pragma unroll
        for (int s = 0; s < 16; ++s)
            acc += *(const v2f*)&HL[i * 32 + 2 * s] * t2[s ^ (i & 15)];
        float wi = acc.x + acc.y;
        if (i & 1) w2[i >> 1].y = wi; else w2[i >> 1].x = wi;
    }

    jacobi_v2(w2, col, base, SW1);

    v2f na = {0.f, 0.f};
    #pragma unroll
    for (int j = 0; j < 16; ++j) na += w2[j] * w2[j];
    const float d2 = na.x + na.y;          // = lambda^2 (symmetric init)
    const float g = 0.5f * logf(d2) / d2;  // log(lam)/lam^2

    // store W columns into tile (pair-swizzled) + to global for pass 2
    const size_t gm = (size_t)blockIdx.x * 8 + matl;
    const int cp = col >> 1, cb = col & 1;
    #pragma unroll
    for (int j = 0; j < 16; ++j) {
        Xm[(2 * j) * 32 + 2 * (cp ^ ((2 * j) & 15)) + cb]         = w2[j].x;
        Xm[(2 * j + 1) * 32 + 2 * (cp ^ ((2 * j + 1) & 15)) + cb] = w2[j].y;
        w1out[gm * 1024 + (2 * j) * 32 + col]     = w2[j].x;
        w1out[gm * 1024 + (2 * j + 1) * 32 + col] = w2[j].y;
    }
    __syncthreads();

    // gr[k] = g_k * W[col,k]
    v2f gr2[16];
    #pragma unroll
    for (int p = 0; p < 16; ++p) {
        v2f wr = *(const v2f*)&Xm[cbase + 2 * (p ^ cm)];
        v2f g2;
        g2.x = __shfl(g, base | (2 * p), 64);
        g2.y = __shfl(g, base | (2 * p + 1), 64);
        gr2[p] = g2 * wr;
    }
    const float invN = 1.0f / (float)NMAT;
    #pragma unroll
    for (int i = 0; i < 32; ++i) {
        v2f acc = {0.f, 0.f};
        #pragma unroll
        for (int s = 0; s < 16; ++s)
            acc += *(const v2f*)&Xm[i * 32 + 2 * s] * gr2[s ^ (i & 15)];
        atomicAdd(&ACC[i * 32 + col], (acc.x + acc.y) * invN);
    }
    __syncthreads();
    for (int e = tid; e < 1024; e += 256)
        atomicAdd(ws + WS_GT + e, ACC[e]);
}

// ---------------------------------------------------------------------------
// K4: E = exp(GT); Gn = Gs E Gs; Gh = Gn^{-1/2}; K = Gh*Gs -> ws[WS_K]
// ---------------------------------------------------------------------------
__global__ __launch_bounds__(64) void k_karcher(float* __restrict__ ws) {
    __shared__ float A[MSZ], V[MSZ], E[MSZ], GS[MSZ], T[MSZ];
    const int lane = threadIdx.x;
    for (int e = lane; e < 1024; e += 64) {
        A[(e >> 5) * MP + (e & 31)]  = ws[WS_GT + e];
        GS[(e >> 5) * MP + (e & 31)] = ws[WS_GS + e];
    }
    __syncthreads();
    jacobi2s(A, V, lane, SW_SINGLE);
    recon_f(A, V, E, lane, 2);        // exp(GT)
    mmul(GS, E, T, lane);             // Gs*E
    mmul(T, GS, A, lane);             // Gn
    jacobi2s(A, V, lane, SW_SINGLE);
    recon_f(A, V, E, lane, 1);        // Gh = Gn^{-1/2}
    mmul(E, GS, T, lane);             // K = Gh*Gs
    for (int e = lane; e < 1024; e += 64) ws[WS_K + e] = T[(e >> 5) * MP + (e & 31)];
}

// ---------------------------------------------------------------------------
// K5 (pass 2, warm): F = K * W1 * diag(||w1||^{-1/2}) (so Xw = F F^T);
// 4-sweep Jacobi; var += sum(log lam)^2; W2 -> wbuf (overwrites W1).
// Factor form: lam_k = ||w2_k||^2.
// ---------------------------------------------------------------------------
__global__ __launch_bounds__(256, 4) void k_batch_warm(float* __restrict__ wbuf,
                                                       float* __restrict__ ws) {
    __shared__ float KL[1024];       // K, natural layout (broadcast reads only)
    __shared__ float VARB;
    const int tid = threadIdx.x;
    if (tid == 0) VARB = 0.f;
    for (int e = tid; e < 1024; e += 256) KL[e] = ws[WS_K + e];
    __syncthreads();

    const int lane = tid & 63;
    const int base = lane & 32;
    const int col  = lane & 31;
    const int matl = (tid >> 6) * 2 + (lane >> 5);
    const size_t gm = (size_t)blockIdx.x * 8 + matl;

    // load own W1 column (row-coalesced)
    float w1[32];
    #pragma unroll
    for (int i = 0; i < 32; ++i) w1[i] = wbuf[gm * 1024 + i * 32 + col];
    float nn = 0.f;
    #pragma unroll
    for (int i = 0; i < 32; ++i) nn += w1[i] * w1[i];
    const float s = rsqrtf(sqrtf(nn));      // ||w1||^{-1/2} = lam1^{-1/2}
    v2f w1s[16];
    #pragma unroll
    for (int j = 0; j < 16; ++j) { w1s[j].x = w1[2 * j] * s; w1s[j].y = w1[2 * j + 1] * s; }

    // F = K * (w1*s)
    v2f w2[16];
    #pragma unroll
    for (int i = 0; i < 32; ++i) {
        v2f acc = {0.f, 0.f};
        #pragma unroll
        for (int j = 0; j < 16; ++j)
            acc += *(const v2f*)&KL[i * 32 + 2 * j] * w1s[j];
        float fi = acc.x + acc.y;
        if (i & 1) w2[i >> 1].y = fi; else w2[i >> 1].x = fi;
    }

    jacobi_v2(w2, col, base, SW2);

    v2f na = {0.f, 0.f};
    #pragma unroll
    for (int j = 0; j < 16; ++j) na += w2[j] * w2[j];
    const float d2 = na.x + na.y;           // = lambda (factor init)
    const float lg = logf(d2);
    float contrib = lg * lg;
    #pragma unroll
    for (int m = 32; m >= 1; m >>= 1) contrib += __shfl_xor(contrib, m, 64);
    if (lane == 0) atomicAdd(&VARB, contrib);

    #pragma unroll
    for (int j = 0; j < 16; ++j) {
        wbuf[gm * 1024 + (2 * j) * 32 + col]     = w2[j].x;
        wbuf[gm * 1024 + (2 * j + 1) * 32 + col] = w2[j].y;
    }
    __syncthreads();
    if (tid == 0) atomicAdd(ws + WS_VAR, VARB * (1.0f / (float)NMAT));
}

// ---------------------------------------------------------------------------
// K6: p = sqrt(1/(var+eps)); Y = C * W2 * diag(lam^{(p-1)/2}); out = Y Y^T.
// ---------------------------------------------------------------------------
__global__ __launch_bounds__(256, 4) void k_final(float* __restrict__ out,
                                                  const float* __restrict__ ws) {
    __shared__ float YL[8 * 1024];   // pair-swizzled Y tiles
    __shared__ float CL[1024];       // C, natural layout
    const int tid = threadIdx.x;
    for (int e = tid; e < 1024; e += 256) CL[e] = ws[WS_C + e];
    __syncthreads();

    const int lane = tid & 63;
    const int col  = lane & 31;
    const int matl = (tid >> 6) * 2 + (lane >> 5);
    const size_t gm = (size_t)blockIdx.x * 8 + matl;
    float* Ym = YL + matl * 1024;
    const int cm = col & 15, cbase = col * 32;

    const float var = ws[WS_VAR];
    const float p = sqrtf(1.0f / (var + 1e-5f));

    // own W2 column from global (row-coalesced)
    float w[32];
    #pragma unroll
    for (int i = 0; i < 32; ++i) w[i] = out[gm * 1024 + i * 32 + col];
    float d2 = 0.f;
    #pragma unroll
    for (int i = 0; i < 32; ++i) d2 += w[i] * w[i];
    const float dj = exp2f(log2f(d2) * 0.5f * (p - 1.0f));  // lam^{(p-1)/2}
    v2f wv2[16];
    #pragma unroll
    for (int j = 0; j < 16; ++j) { wv2[j].x = w[2 * j]; wv2[j].y = w[2 * j + 1]; }

    // y = C * w * dj  -> into Ym (pair-swizzled)
    const int cp = col >> 1, cb = col & 1;
    #pragma unroll
    for (int i = 0; i < 32; ++i) {
        v2f acc = {0.f, 0.f};
        #pragma unroll
        for (int j = 0; j < 16; ++j)
            acc += *(const v2f*)&CL[i * 32 + 2 * j] * wv2[j];
        Ym[i * 32 + 2 * (cp ^ (i & 15)) + cb] = (acc.x + acc.y) * dj;
    }
    __syncthreads();

    // yr = row col of Y; out rows = Y * yr
    v2f yr2[16];
    #pragma unroll
    for (int pp = 0; pp < 16; ++pp) yr2[pp] = *(const v2f*)&YL[matl * 1024 + cbase + 2 * (pp ^ cm)];
    #pragma unroll
    for (int i = 0; i < 32; ++i) {
        v2f acc = {0.f, 0.f};
        #pragma unroll
        for (int s2 = 0; s2 < 16; ++s2)
            acc += *(const v2f*)&Ym[i * 32 + 2 * s2] * yr2[s2 ^ (i & 15)];
        out[gm * 1024 + i * 32 + col] = acc.x + acc.y;
    }
}

extern "C" void kernel_launch(void* const* d_in, const int* in_sizes, int n_in,
                              void* d_out, int out_size, void* d_ws, size_t ws_size,
                              hipStream_t stream) {
    const float* X = (const float*)d_in[0];
    const float* R = (const float*)d_in[1];
    const float* B = (const float*)d_in[2];
    float* out = (float*)d_out;
    float* ws  = (float*)d_ws;

    hipMemsetAsync(d_ws, 0, WS_TOTAL * sizeof(float), stream);
    k_mean<<<NMAT / 64, 256, 0, stream>>>(X, ws);
    k_small_prep<<<2, 64, 0, stream>>>(R, B, ws);
    k_batch_log<<<NMAT / 8, 256, 0, stream>>>(X, out, ws);
    k_karcher<<<1, 64, 0, stream>>>(ws);
    k_batch_warm<<<NMAT / 8, 256, 0, stream>>>(out, ws);
    k_final<<<NMAT / 8, 256, 0, stream>>>(out, ws);
}

// Round 3
// 3997.864 us; speedup vs baseline: 1.5751x; 1.0199x over previous
//
#include <hip/hip_runtime.h>
#include <math.h>

typedef float v2f __attribute__((ext_vector_type(2)));
typedef float v4f __attribute__((ext_vector_type(4)));

#define MP 33
#define MSZ (32 * MP)
#define NMAT 32768
#define SW1 6          // pass-1 sweeps (cold start)
#define SW2 3          // pass-2 sweeps (warm start; quadratic convergence)
#define SW_SINGLE 10

// workspace float offsets
#define WS_G    0
#define WS_GS   1024
#define WS_GIS  2048
#define WS_GT   3072
#define WS_K    4096
#define WS_C    5120
#define WS_VAR  6144
#define WS_TOTAL 6400

// pair-swizzled 32x32 tile: element (r,c) at r*32 + 2*((c>>1)^(r&15)) + (c&1).
__device__ __forceinline__ int swz(int r, int c) {
    return r * 32 + 2 * ((c >> 1) ^ (r & 15)) + (c & 1);
}

// ---------------------------------------------------------------------------
// One-sided Jacobi, fast-Givens form (scaled columns), XOR tournament.
// Lane owns one column in 16 v2f regs. Returns final true squared norm.
// ---------------------------------------------------------------------------
__device__ __forceinline__ float jacobi_fg(v2f (&v)[16], int col, int sweeps) {
    float dn = 0.f;
    #pragma unroll 1
    for (int sweep = 0; sweep < sweeps; ++sweep) {
        v2f na = {0.f, 0.f};
        #pragma unroll
        for (int j = 0; j < 16; ++j) na += v[j] * v[j];
        dn = na.x + na.y;                 // fresh true norm^2 (sc==1 here)
        float sc = 1.f, rsc = 1.f;
        #pragma unroll 1
        for (int m = 1; m < 32; ++m) {
            v2f o[16];
            #pragma unroll
            for (int j = 0; j < 16; ++j) {
                o[j].x = __shfl_xor(v[j].x, m, 64);
                o[j].y = __shfl_xor(v[j].y, m, 64);
            }
            v2f pr = {0.f, 0.f};
            #pragma unroll
            for (int j = 0; j < 16; ++j) pr += v[j] * o[j];
            const float raw  = pr.x + pr.y;
            const float dq   = __shfl_xor(sc, m, 64);
            const float dnq  = __shfl_xor(dn, m, 64);
            const float apq  = sc * dq * raw;
            const bool  isp  = col < (col ^ m);
            const float app  = isp ? dn : dnq;
            const float aqq  = isp ? dnq : dn;
            // rotation (branchless; inf/NaN path masked by ok-select)
            const float th  = (aqq - app) * __builtin_amdgcn_rcpf(2.f * apq);
            const float q1  = __builtin_amdgcn_sqrtf(__builtin_fmaf(th, th, 1.f));
            const float t0  = copysignf(__builtin_amdgcn_rcpf(fabsf(th) + q1), th);
            const float s1  = __builtin_fmaf(t0, t0, 1.f);
            const float c0  = __builtin_amdgcn_rsqf(s1);
            const float rc0 = c0 * s1;    // = sqrt(s1) = 1/c
            const bool ok = fabsf(apq) > 1e-30f;
            const float t  = ok ? t0 : 0.f;
            const float c  = ok ? c0 : 1.f;
            const float rc = ok ? rc0 : 1.f;
            const float gam = t * dq * rsc;
            const float gs  = isp ? -gam : gam;
            const v2f gs2 = {gs, gs};
            #pragma unroll
            for (int j = 0; j < 16; ++j) v[j] += gs2 * o[j];
            sc *= c; rsc *= rc;
            dn = __builtin_fmaf(isp ? -t : t, apq, dn);
        }
        const v2f s2 = {sc, sc};
        #pragma unroll
        for (int j = 0; j < 16; ++j) v[j] *= s2;   // fold scale back in
    }
    v2f na = {0.f, 0.f};
    #pragma unroll
    for (int j = 0; j < 16; ++j) na += v[j] * v[j];
    return na.x + na.y;
}

// ---------------------------------------------------------------------------
// Two-sided Jacobi for the single small matrices (unchanged).
// ---------------------------------------------------------------------------
__device__ void jacobi2s(float* A, float* V, int lane, int sweeps) {
    const int col = lane & 31;
    const int r0  = (lane >> 5) * 16;
    for (int ii = 0; ii < 16; ++ii) V[(r0 + ii) * MP + col] = ((r0 + ii) == col) ? 1.f : 0.f;
    __syncthreads();
    for (int sw = 0; sw < sweeps; ++sw) {
        for (int r = 0; r < 31; ++r) {
            int part = (col == 31) ? r : ((col == r) ? 31 : ((2 * r - col + 62) % 31));
            int p = col < part ? col : part;
            int q = col < part ? part : col;
            bool isp = (col == p);
            float app = A[p * MP + p], aqq = A[q * MP + q], apq = A[p * MP + q];
            float c = 1.f, sn = 0.f;
            if (fabsf(apq) > 1e-35f) {
                float th = (aqq - app) / (2.f * apq);
                float t  = copysignf(1.f, th) / (fabsf(th) + sqrtf(1.f + th * th));
                c  = rsqrtf(1.f + t * t);
                sn = t * c;
            }
            float tmp[16];
            #pragma unroll
            for (int ii = 0; ii < 16; ++ii) {
                float xp = A[(r0 + ii) * MP + p], xq = A[(r0 + ii) * MP + q];
                tmp[ii] = isp ? (c * xp - sn * xq) : (sn * xp + c * xq);
            }
            __syncthreads();
            #pragma unroll
            for (int ii = 0; ii < 16; ++ii) A[(r0 + ii) * MP + col] = tmp[ii];
            __syncthreads();
            #pragma unroll
            for (int ii = 0; ii < 16; ++ii) {
                float rp = A[p * MP + (r0 + ii)], rq = A[q * MP + (r0 + ii)];
                tmp[ii] = isp ? (c * rp - sn * rq) : (sn * rp + c * rq);
            }
            __syncthreads();
            #pragma unroll
            for (int ii = 0; ii < 16; ++ii) A[col * MP + (r0 + ii)] = tmp[ii];
            __syncthreads();
            #pragma unroll
            for (int ii = 0; ii < 16; ++ii) {
                float xp = V[(r0 + ii) * MP + p], xq = V[(r0 + ii) * MP + q];
                tmp[ii] = isp ? (c * xp - sn * xq) : (sn * xp + c * xq);
            }
            __syncthreads();
            #pragma unroll
            for (int ii = 0; ii < 16; ++ii) V[(r0 + ii) * MP + col] = tmp[ii];
            __syncthreads();
        }
    }
}

__device__ void recon_f(const float* A, const float* V, float* O, int lane, int mode) {
    const int col = lane & 31;
    const int r0  = (lane >> 5) * 16;
    float fv[32];
    #pragma unroll
    for (int k = 0; k < 32; ++k) {
        float lam = A[k * MP + k];
        float f = (mode == 0) ? sqrtf(lam) : (mode == 1) ? rsqrtf(lam) : expf(lam);
        fv[k] = f * V[col * MP + k];
    }
    __syncthreads();
    for (int i = r0; i < r0 + 16; ++i) {
        float a = 0.f;
        #pragma unroll
        for (int k = 0; k < 32; ++k) a += V[i * MP + k] * fv[k];
        O[i * MP + col] = a;
    }
    __syncthreads();
}

__device__ void mmul(const float* P, const float* Q, float* O, int lane) {
    const int col = lane & 31;
    const int r0  = (lane >> 5) * 16;
    for (int i = r0; i < r0 + 16; ++i) {
        float a = 0.f;
        #pragma unroll
        for (int k = 0; k < 32; ++k) a += P[i * MP + k] * Q[k * MP + col];
        O[i * MP + col] = a;
    }
    __syncthreads();
}

// ---------------------------------------------------------------------------
// K1: arithmetic mean -> ws[WS_G]
// ---------------------------------------------------------------------------
__global__ __launch_bounds__(256) void k_mean(const float* __restrict__ X,
                                              float* __restrict__ ws) {
    const int t = threadIdx.x;
    const size_t base = (size_t)blockIdx.x * 64 * 1024;
    float4 a = {0.f, 0.f, 0.f, 0.f};
    for (int m = 0; m < 64; ++m) {
        float4 f = *(const float4*)&X[base + (size_t)m * 1024 + t * 4];
        a.x += f.x; a.y += f.y; a.z += f.z; a.w += f.w;
    }
    const float s = 1.0f / (float)NMAT;
    atomicAdd(ws + WS_G + 4 * t + 0, a.x * s);
    atomicAdd(ws + WS_G + 4 * t + 1, a.y * s);
    atomicAdd(ws + WS_G + 4 * t + 2, a.z * s);
    atomicAdd(ws + WS_G + 4 * t + 3, a.w * s);
}

// ---------------------------------------------------------------------------
// K2: block 0: eig(G) -> Gs, Gis.  block 1: eig(B) -> C = B^{1/2} R.
// ---------------------------------------------------------------------------
__global__ __launch_bounds__(64) void k_small_prep(const float* __restrict__ R,
                                                   const float* __restrict__ B,
                                                   float* __restrict__ ws) {
    __shared__ float A[MSZ], V[MSZ], T1[MSZ], T2[MSZ];
    const int lane = threadIdx.x;
    if (blockIdx.x == 0) {
        for (int e = lane; e < 1024; e += 64) A[(e >> 5) * MP + (e & 31)] = ws[WS_G + e];
        __syncthreads();
        jacobi2s(A, V, lane, SW_SINGLE);
        recon_f(A, V, T1, lane, 0);   // Gs
        recon_f(A, V, T2, lane, 1);   // Gis
        for (int e = lane; e < 1024; e += 64) {
            ws[WS_GS + e]  = T1[(e >> 5) * MP + (e & 31)];
            ws[WS_GIS + e] = T2[(e >> 5) * MP + (e & 31)];
        }
    } else {
        for (int e = lane; e < 1024; e += 64) A[(e >> 5) * MP + (e & 31)] = B[e];
        __syncthreads();
        jacobi2s(A, V, lane, SW_SINGLE);
        recon_f(A, V, T1, lane, 0);   // Bs
        for (int e = lane; e < 1024; e += 64) T2[(e >> 5) * MP + (e & 31)] = R[e];
        __syncthreads();
        mmul(T1, T2, V, lane);        // C = Bs * R
        for (int e = lane; e < 1024; e += 64) ws[WS_C + e] = V[(e >> 5) * MP + (e & 31)];
    }
}

// ---------------------------------------------------------------------------
// K3 (pass 1): M = Gis X Gis (X rows broadcast from GLOBAL; only Gis in LDS);
// fast-Givens Jacobi; W1 -> w1out. LDS-light for occupancy.
// ---------------------------------------------------------------------------
__global__ __launch_bounds__(256, 6) void k_batch_log(const float* __restrict__ X,
                                                      float* __restrict__ w1out,
                                                      const float* __restrict__ ws) {
    __shared__ float HL[1024];       // Gis, pair-swizzled
    const int tid = threadIdx.x;
    for (int e = tid; e < 1024; e += 256) {
        int r = e >> 5, c = e & 31;
        HL[swz(r, c)] = ws[WS_GIS + e];
    }
    __syncthreads();

    const int lane = tid & 63;
    const int col  = lane & 31;
    const int matl = (tid >> 6) * 2 + (lane >> 5);
    const size_t gm = (size_t)blockIdx.x * 8 + matl;
    const float* Xm = X + gm * 1024;
    const int cm = col & 15, cbase = col * 32;

    // h2[p] = Gis[col, 2p..2p+1]
    v2f h2[16];
    #pragma unroll
    for (int p = 0; p < 16; ++p) h2[p] = *(const v2f*)&HL[cbase + 2 * (p ^ cm)];

    // t = X * h  (X rows uniform per half-wave -> broadcast loads)
    v2f t2[16];
    #pragma unroll
    for (int i = 0; i < 32; ++i) {
        const float4* row = (const float4*)(Xm + i * 32);
        v2f acc = {0.f, 0.f};
        #pragma unroll
        for (int q = 0; q < 8; ++q) {
            float4 f = row[q];
            v2f lo = {f.x, f.y}, hi = {f.z, f.w};
            acc += lo * h2[2 * q] + hi * h2[2 * q + 1];
        }
        float ti = acc.x + acc.y;
        if (i & 1) t2[i >> 1].y = ti; else t2[i >> 1].x = ti;
    }
    // v = Gis * t  (LDS b128 broadcast, swizzled)
    v2f v[16];
    #pragma unroll
    for (int i = 0; i < 32; ++i) {
        v2f acc = {0.f, 0.f};
        const int tw = i & 15;
        #pragma unroll
        for (int q = 0; q < 8; ++q) {
            v4f f = *(const v4f*)&HL[i * 32 + 4 * q];
            v2f lo = {f.x, f.y}, hi = {f.z, f.w};
            acc += lo * t2[(2 * q) ^ tw] + hi * t2[(2 * q + 1) ^ tw];
        }
        float wi = acc.x + acc.y;
        if (i & 1) v[i >> 1].y = wi; else v[i >> 1].x = wi;
    }

    jacobi_fg(v, col, SW1);

    float* outp = w1out + gm * 1024 + col;
    #pragma unroll
    for (int j = 0; j < 16; ++j) {
        outp[(2 * j) * 32]     = v[j].x;
        outp[(2 * j + 1) * 32] = v[j].y;
    }
}

// ---------------------------------------------------------------------------
// K3b: GT += mean over matrices of W*diag(log(lam)/lam^2)*W^T  (reads W1).
// ---------------------------------------------------------------------------
__global__ __launch_bounds__(256, 4) void k_gt(const float* __restrict__ w1,
                                               float* __restrict__ ws) {
    __shared__ float WL[8 * 1024];   // pair-swizzled W tiles
    __shared__ float ACC[1024];
    const int tid = threadIdx.x;
    for (int e = tid; e < 1024; e += 256) ACC[e] = 0.f;
    const size_t gbase = (size_t)blockIdx.x * 8192;
    for (int e2 = tid; e2 < 4096; e2 += 256) {
        int mat = e2 >> 9, rp = e2 & 511, r = rp >> 4, p = rp & 15;
        v2f val = *(const v2f*)&w1[gbase + mat * 1024 + r * 32 + 2 * p];
        *(v2f*)&WL[mat * 1024 + r * 32 + 2 * (p ^ (r & 15))] = val;
    }
    __syncthreads();

    const int lane = tid & 63;
    const int base = lane & 32;
    const int col  = lane & 31;
    const int matl = (tid >> 6) * 2 + (lane >> 5);
    float* Wm = WL + matl * 1024;
    const int cm = col & 15, cbase = col * 32;

    // column norm^2 = lam^2
    float dn = 0.f;
    #pragma unroll
    for (int r = 0; r < 32; ++r) {
        float x = Wm[r * 32 + 2 * ((col >> 1) ^ (r & 15)) + (col & 1)];
        dn = __builtin_fmaf(x, x, dn);
    }
    const float g = 0.5f * logf(dn) * __builtin_amdgcn_rcpf(dn);

    // gr[k] = g_k * W[col,k]
    v2f gr2[16];
    #pragma unroll
    for (int p = 0; p < 16; ++p) {
        v2f wr = *(const v2f*)&Wm[cbase + 2 * (p ^ cm)];
        v2f g2;
        g2.x = __shfl(g, base | (2 * p), 64);
        g2.y = __shfl(g, base | (2 * p + 1), 64);
        gr2[p] = g2 * wr;
    }
    const float invN = 1.0f / (float)NMAT;
    #pragma unroll
    for (int i = 0; i < 32; ++i) {
        v2f acc = {0.f, 0.f};
        const int tw = i & 15;
        #pragma unroll
        for (int q = 0; q < 8; ++q) {
            v4f f = *(const v4f*)&Wm[i * 32 + 4 * q];
            v2f lo = {f.x, f.y}, hi = {f.z, f.w};
            acc += lo * gr2[(2 * q) ^ tw] + hi * gr2[(2 * q + 1) ^ tw];
        }
        atomicAdd(&ACC[i * 32 + col], (acc.x + acc.y) * invN);
    }
    __syncthreads();
    for (int e = tid; e < 1024; e += 256) atomicAdd(ws + WS_GT + e, ACC[e]);
}

// ---------------------------------------------------------------------------
// K4: E = exp(GT); Gn = Gs E Gs; Gh = Gn^{-1/2}; K = Gh*Gs -> ws[WS_K]
// ---------------------------------------------------------------------------
__global__ __launch_bounds__(64) void k_karcher(float* __restrict__ ws) {
    __shared__ float A[MSZ], V[MSZ], E[MSZ], GS[MSZ], T[MSZ];
    const int lane = threadIdx.x;
    for (int e = lane; e < 1024; e += 64) {
        A[(e >> 5) * MP + (e & 31)]  = ws[WS_GT + e];
        GS[(e >> 5) * MP + (e & 31)] = ws[WS_GS + e];
    }
    __syncthreads();
    jacobi2s(A, V, lane, SW_SINGLE);
    recon_f(A, V, E, lane, 2);        // exp(GT)
    mmul(GS, E, T, lane);             // Gs*E
    mmul(T, GS, A, lane);             // Gn
    jacobi2s(A, V, lane, SW_SINGLE);
    recon_f(A, V, E, lane, 1);        // Gh = Gn^{-1/2}
    mmul(E, GS, T, lane);             // K = Gh*Gs
    for (int e = lane; e < 1024; e += 64) ws[WS_K + e] = T[(e >> 5) * MP + (e & 31)];
}

// ---------------------------------------------------------------------------
// K5 (pass 2, warm): F = K * W1 * diag(lam1^{-1/2}); 3-sweep Jacobi;
// var += sum(log lam)^2; W2 -> wbuf (overwrites W1). lam_k = ||f_k||^2.
// ---------------------------------------------------------------------------
__global__ __launch_bounds__(256, 6) void k_batch_warm(float* __restrict__ wbuf,
                                                       float* __restrict__ ws) {
    __shared__ float KL[1024];       // K, natural (broadcast reads only)
    __shared__ float VARB;
    const int tid = threadIdx.x;
    if (tid == 0) VARB = 0.f;
    for (int e = tid; e < 1024; e += 256) KL[e] = ws[WS_K + e];
    __syncthreads();

    const int lane = tid & 63;
    const int col  = lane & 31;
    const int matl = (tid >> 6) * 2 + (lane >> 5);
    const size_t gm = (size_t)blockIdx.x * 8 + matl;
    float* wp = wbuf + gm * 1024 + col;

    float w1[32];
    #pragma unroll
    for (int i = 0; i < 32; ++i) w1[i] = wp[i * 32];
    float nn = 0.f;
    #pragma unroll
    for (int i = 0; i < 32; ++i) nn = __builtin_fmaf(w1[i], w1[i], nn);
    const float s = __builtin_amdgcn_rsqf(__builtin_amdgcn_sqrtf(nn));  // lam1^{-1/2}
    v2f w1s[16];
    #pragma unroll
    for (int j = 0; j < 16; ++j) { w1s[j].x = w1[2 * j] * s; w1s[j].y = w1[2 * j + 1] * s; }

    v2f v[16];
    #pragma unroll
    for (int i = 0; i < 32; ++i) {
        v2f acc = {0.f, 0.f};
        #pragma unroll
        for (int q = 0; q < 8; ++q) {
            v4f f = *(const v4f*)&KL[i * 32 + 4 * q];
            v2f lo = {f.x, f.y}, hi = {f.z, f.w};
            acc += lo * w1s[2 * q] + hi * w1s[2 * q + 1];
        }
        float fi = acc.x + acc.y;
        if (i & 1) v[i >> 1].y = fi; else v[i >> 1].x = fi;
    }

    const float dn = jacobi_fg(v, col, SW2);   // = lambda (factor init)
    const float lg = logf(dn);
    float contrib = lg * lg;
    #pragma unroll
    for (int m = 32; m >= 1; m >>= 1) contrib += __shfl_xor(contrib, m, 64);
    if (lane == 0) atomicAdd(&VARB, contrib);

    #pragma unroll
    for (int j = 0; j < 16; ++j) {
        wp[(2 * j) * 32]     = v[j].x;
        wp[(2 * j + 1) * 32] = v[j].y;
    }
    __syncthreads();
    if (tid == 0) atomicAdd(ws + WS_VAR, VARB * (1.0f / (float)NMAT));
}

// ---------------------------------------------------------------------------
// K6: p = sqrt(1/(var+eps)); Y = C * W2 * diag(lam^{(p-1)/2}); out = Y Y^T.
// ---------------------------------------------------------------------------
__global__ __launch_bounds__(256, 4) void k_final(float* __restrict__ out,
                                                  const float* __restrict__ ws) {
    __shared__ float YL[8 * 1024];   // pair-swizzled Y tiles
    __shared__ float CL[1024];       // C, natural layout
    const int tid = threadIdx.x;
    for (int e = tid; e < 1024; e += 256) CL[e] = ws[WS_C + e];
    __syncthreads();

    const int lane = tid & 63;
    const int col  = lane & 31;
    const int matl = (tid >> 6) * 2 + (lane >> 5);
    const size_t gm = (size_t)blockIdx.x * 8 + matl;
    float* Ym = YL + matl * 1024;
    const int cm = col & 15, cbase = col * 32;

    const float var = ws[WS_VAR];
    const float p = sqrtf(1.0f / (var + 1e-5f));

    float w[32];
    #pragma unroll
    for (int i = 0; i < 32; ++i) w[i] = out[gm * 1024 + i * 32 + col];
    float d2 = 0.f;
    #pragma unroll
    for (int i = 0; i < 32; ++i) d2 += w[i] * w[i];
    const float dj = exp2f(log2f(d2) * 0.5f * (p - 1.0f));  // lam^{(p-1)/2}
    v2f wv2[16];
    #pragma unroll
    for (int j = 0; j < 16; ++j) { wv2[j].x = w[2 * j]; wv2[j].y = w[2 * j + 1]; }

    const int cp = col >> 1, cb = col & 1;
    #pragma unroll
    for (int i = 0; i < 32; ++i) {
        v2f acc = {0.f, 0.f};
        #pragma unroll
        for (int j = 0; j < 16; ++j)
            acc += *(const v2f*)&CL[i * 32 + 2 * j] * wv2[j];
        Ym[i * 32 + 2 * (cp ^ (i & 15)) + cb] = (acc.x + acc.y) * dj;
    }
    __syncthreads();

    v2f yr2[16];
    #pragma unroll
    for (int pp = 0; pp < 16; ++pp) yr2[pp] = *(const v2f*)&YL[matl * 1024 + cbase + 2 * (pp ^ cm)];
    #pragma unroll
    for (int i = 0; i < 32; ++i) {
        v2f acc = {0.f, 0.f};
        #pragma unroll
        for (int s2 = 0; s2 < 16; ++s2)
            acc += *(const v2f*)&Ym[i * 32 + 2 * s2] * yr2[s2 ^ (i & 15)];
        out[gm * 1024 + i * 32 + col] = acc.x + acc.y;
    }
}

extern "C" void kernel_launch(void* const* d_in, const int* in_sizes, int n_in,
                              void* d_out, int out_size, void* d_ws, size_t ws_size,
                              hipStream_t stream) {
    const float* X = (const float*)d_in[0];
    const float* R = (const float*)d_in[1];
    const float* B = (const float*)d_in[2];
    float* out = (float*)d_out;
    float* ws  = (float*)d_ws;

    hipMemsetAsync(d_ws, 0, WS_TOTAL * sizeof(float), stream);
    k_mean<<<NMAT / 64, 256, 0, stream>>>(X, ws);
    k_small_prep<<<2, 64, 0, stream>>>(R, B, ws);
    k_batch_log<<<NMAT / 8, 256, 0, stream>>>(X, out, ws);
    k_gt<<<NMAT / 8, 256, 0, stream>>>(out, ws);
    k_karcher<<<1, 64, 0, stream>>>(ws);
    k_batch_warm<<<NMAT / 8, 256, 0, stream>>>(out, ws);
    k_final<<<NMAT / 8, 256, 0, stream>>>(out, ws);
}

// Round 4
// 2565.364 us; speedup vs baseline: 2.4547x; 1.5584x over previous
//
#include <hip/hip_runtime.h>
#include <math.h>

typedef float v2f __attribute__((ext_vector_type(2)));
typedef float v4f __attribute__((ext_vector_type(4)));

#define NMAT 32768
#define SW1 6          // pass-1 sweeps (cold start)
#define SW2 3          // pass-2 sweeps (warm start)
#define SW_SINGLE 10   // single-matrix eigs (off critical path cost-wise)
#define SP 34          // padded row stride for single-wave LDS matrices

// workspace float offsets
#define WS_G    0
#define WS_GS   1024
#define WS_GIS  2048
#define WS_GT   3072
#define WS_K    4096
#define WS_C    5120
#define WS_VAR  6144
#define WS_TOTAL 6400

// pair-swizzled 32x32 tile: element (r,c) at r*32 + 2*((c>>1)^(r&15)) + (c&1).
__device__ __forceinline__ int swz(int r, int c) {
    return r * 32 + 2 * ((c >> 1) ^ (r & 15)) + (c & 1);
}

// ---------------------------------------------------------------------------
// One-sided Jacobi, fast-Givens form (scaled columns), XOR tournament.
// Lane owns one column in 16 v2f regs. Returns final true squared norm.
// ---------------------------------------------------------------------------
__device__ __forceinline__ float jacobi_fg(v2f (&v)[16], int col, int sweeps) {
    float dn = 0.f;
    #pragma unroll 1
    for (int sweep = 0; sweep < sweeps; ++sweep) {
        v2f na = {0.f, 0.f};
        #pragma unroll
        for (int j = 0; j < 16; ++j) na += v[j] * v[j];
        dn = na.x + na.y;                 // fresh true norm^2 (sc==1 here)
        float sc = 1.f, rsc = 1.f;
        #pragma unroll 1
        for (int m = 1; m < 32; ++m) {
            v2f o[16];
            #pragma unroll
            for (int j = 0; j < 16; ++j) {
                o[j].x = __shfl_xor(v[j].x, m, 64);
                o[j].y = __shfl_xor(v[j].y, m, 64);
            }
            v2f pr = {0.f, 0.f};
            #pragma unroll
            for (int j = 0; j < 16; ++j) pr += v[j] * o[j];
            const float raw  = pr.x + pr.y;
            const float dq   = __shfl_xor(sc, m, 64);
            const float dnq  = __shfl_xor(dn, m, 64);
            const float apq  = sc * dq * raw;
            const bool  isp  = col < (col ^ m);
            const float app  = isp ? dn : dnq;
            const float aqq  = isp ? dnq : dn;
            const float th  = (aqq - app) * __builtin_amdgcn_rcpf(2.f * apq);
            const float q1  = __builtin_amdgcn_sqrtf(__builtin_fmaf(th, th, 1.f));
            const float t0  = copysignf(__builtin_amdgcn_rcpf(fabsf(th) + q1), th);
            const float s1  = __builtin_fmaf(t0, t0, 1.f);
            const float c0  = __builtin_amdgcn_rsqf(s1);
            const float rc0 = c0 * s1;    // = sqrt(s1) = 1/c
            const bool ok = fabsf(apq) > 1e-30f;
            const float t  = ok ? t0 : 0.f;
            const float c  = ok ? c0 : 1.f;
            const float rc = ok ? rc0 : 1.f;
            const float gam = t * dq * rsc;
            const float gs  = isp ? -gam : gam;
            const v2f gs2 = {gs, gs};
            #pragma unroll
            for (int j = 0; j < 16; ++j) v[j] += gs2 * o[j];
            sc *= c; rsc *= rc;
            dn = __builtin_fmaf(isp ? -t : t, apq, dn);
        }
        const v2f s2 = {sc, sc};
        #pragma unroll
        for (int j = 0; j < 16; ++j) v[j] *= s2;   // fold scale back in
    }
    v2f na = {0.f, 0.f};
    #pragma unroll
    for (int j = 0; j < 16; ++j) na += v[j] * v[j];
    return na.x + na.y;
}

// ---------------------------------------------------------------------------
// Single-wave helpers (64-thread blocks; both 32-lane halves duplicate work).
// LDS matrices are row-major with stride SP; rows are read wave-uniformly
// (broadcast, conflict-free); column writes are lane-consecutive.
// ---------------------------------------------------------------------------
__device__ __forceinline__ void put_col(float* L, const v2f (&w)[16], int col) {
    #pragma unroll
    for (int j = 0; j < 16; ++j) {
        L[(2 * j) * SP + col]     = w[j].x;
        L[(2 * j + 1) * SP + col] = w[j].y;
    }
}

// z = M(L) * y
__device__ __forceinline__ void colmm(const float* L, const v2f (&y)[16], v2f (&z)[16]) {
    #pragma unroll
    for (int i = 0; i < 32; ++i) {
        v2f acc = {0.f, 0.f};
        #pragma unroll
        for (int q = 0; q < 16; ++q) {
            v2f mm = *(const v2f*)&L[i * SP + 2 * q];
            acc += mm * y[q];
        }
        float zi = acc.x + acc.y;
        if (i & 1) z[i >> 1].y = zi; else z[i >> 1].x = zi;
    }
}

// O column col of  W diag(coef) W^T, given W in LDS and per-lane coef.
__device__ __forceinline__ void recon_col(const float* LW, float coef, int col,
                                          int base, v2f (&z)[16]) {
    float rv[32];
    #pragma unroll
    for (int k = 0; k < 32; ++k) rv[k] = LW[col * SP + k];
    v2f y[16];
    #pragma unroll
    for (int q = 0; q < 16; ++q) {
        y[q].x = __shfl(coef, base | (2 * q), 64)     * rv[2 * q];
        y[q].y = __shfl(coef, base | (2 * q + 1), 64) * rv[2 * q + 1];
    }
    colmm(LW, y, z);
}

// ---------------------------------------------------------------------------
// K1: arithmetic mean -> ws[WS_G]
// ---------------------------------------------------------------------------
__global__ __launch_bounds__(256) void k_mean(const float* __restrict__ X,
                                              float* __restrict__ ws) {
    const int t = threadIdx.x;
    const size_t base = (size_t)blockIdx.x * 64 * 1024;
    float4 a = {0.f, 0.f, 0.f, 0.f};
    for (int m = 0; m < 64; ++m) {
        float4 f = *(const float4*)&X[base + (size_t)m * 1024 + t * 4];
        a.x += f.x; a.y += f.y; a.z += f.z; a.w += f.w;
    }
    const float s = 1.0f / (float)NMAT;
    atomicAdd(ws + WS_G + 4 * t + 0, a.x * s);
    atomicAdd(ws + WS_G + 4 * t + 1, a.y * s);
    atomicAdd(ws + WS_G + 4 * t + 2, a.z * s);
    atomicAdd(ws + WS_G + 4 * t + 3, a.w * s);
}

// ---------------------------------------------------------------------------
// K2: block 0: eig(G) -> Gs, Gis.  block 1: eig(B) -> C = B^{1/2} R.
// Register one-sided Jacobi + LDS broadcast reconstruction (single wave).
// ---------------------------------------------------------------------------
__global__ __launch_bounds__(64) void k_small_prep(const float* __restrict__ R,
                                                   const float* __restrict__ B,
                                                   float* __restrict__ ws) {
    __shared__ float LW[32 * SP];
    const int lane = threadIdx.x;
    const int col  = lane & 31;
    const int base = lane & 32;
    if (blockIdx.x == 0) {
        v2f w[16];
        #pragma unroll
        for (int j = 0; j < 16; ++j) {
            w[j].x = ws[WS_G + (2 * j) * 32 + col];
            w[j].y = ws[WS_G + (2 * j + 1) * 32 + col];
        }
        const float dn = jacobi_fg(w, col, SW_SINGLE);   // dn = lam^2
        put_col(LW, w, col);
        __syncthreads();
        const float lam = __builtin_amdgcn_sqrtf(dn);
        const float cs  = __builtin_amdgcn_sqrtf(lam) * __builtin_amdgcn_rcpf(dn);
        const float cis = __builtin_amdgcn_rsqf(lam)  * __builtin_amdgcn_rcpf(dn);
        v2f z[16];
        recon_col(LW, cs, col, base, z);    // Gs = W diag(sqrt(lam)/lam^2) W^T
        #pragma unroll
        for (int j = 0; j < 16; ++j) {
            ws[WS_GS + (2 * j) * 32 + col]     = z[j].x;
            ws[WS_GS + (2 * j + 1) * 32 + col] = z[j].y;
        }
        recon_col(LW, cis, col, base, z);   // Gis
        #pragma unroll
        for (int j = 0; j < 16; ++j) {
            ws[WS_GIS + (2 * j) * 32 + col]     = z[j].x;
            ws[WS_GIS + (2 * j + 1) * 32 + col] = z[j].y;
        }
    } else {
        v2f w[16];
        #pragma unroll
        for (int j = 0; j < 16; ++j) {
            w[j].x = B[(2 * j) * 32 + col];
            w[j].y = B[(2 * j + 1) * 32 + col];
        }
        const float dn = jacobi_fg(w, col, SW_SINGLE);
        put_col(LW, w, col);
        __syncthreads();
        const float lam = __builtin_amdgcn_sqrtf(dn);
        const float cbs = __builtin_amdgcn_sqrtf(lam) * __builtin_amdgcn_rcpf(dn);
        v2f bs[16];
        recon_col(LW, cbs, col, base, bs);  // Bs = B^{1/2}
        __syncthreads();
        put_col(LW, bs, col);               // LW <- Bs
        __syncthreads();
        v2f r[16];
        #pragma unroll
        for (int j = 0; j < 16; ++j) {
            r[j].x = R[(2 * j) * 32 + col];
            r[j].y = R[(2 * j + 1) * 32 + col];
        }
        v2f c[16];
        colmm(LW, r, c);                    // C = Bs * R
        #pragma unroll
        for (int j = 0; j < 16; ++j) {
            ws[WS_C + (2 * j) * 32 + col]     = c[j].x;
            ws[WS_C + (2 * j + 1) * 32 + col] = c[j].y;
        }
    }
}

// ---------------------------------------------------------------------------
// K3 (pass 1): M = Gis X Gis (X rows broadcast from GLOBAL; only Gis in LDS);
// fast-Givens Jacobi; W1 -> w1out.
// ---------------------------------------------------------------------------
__global__ __launch_bounds__(256, 6) void k_batch_log(const float* __restrict__ X,
                                                      float* __restrict__ w1out,
                                                      const float* __restrict__ ws) {
    __shared__ float HL[1024];       // Gis, pair-swizzled
    const int tid = threadIdx.x;
    for (int e = tid; e < 1024; e += 256) {
        int r = e >> 5, c = e & 31;
        HL[swz(r, c)] = ws[WS_GIS + e];
    }
    __syncthreads();

    const int lane = tid & 63;
    const int col  = lane & 31;
    const int matl = (tid >> 6) * 2 + (lane >> 5);
    const size_t gm = (size_t)blockIdx.x * 8 + matl;
    const float* Xm = X + gm * 1024;
    const int cm = col & 15, cbase = col * 32;

    v2f h2[16];
    #pragma unroll
    for (int p = 0; p < 16; ++p) h2[p] = *(const v2f*)&HL[cbase + 2 * (p ^ cm)];

    v2f t2[16];
    #pragma unroll
    for (int i = 0; i < 32; ++i) {
        const float4* row = (const float4*)(Xm + i * 32);
        v2f acc = {0.f, 0.f};
        #pragma unroll
        for (int q = 0; q < 8; ++q) {
            float4 f = row[q];
            v2f lo = {f.x, f.y}, hi = {f.z, f.w};
            acc += lo * h2[2 * q] + hi * h2[2 * q + 1];
        }
        float ti = acc.x + acc.y;
        if (i & 1) t2[i >> 1].y = ti; else t2[i >> 1].x = ti;
    }
    v2f v[16];
    #pragma unroll
    for (int i = 0; i < 32; ++i) {
        v2f acc = {0.f, 0.f};
        const int tw = i & 15;
        #pragma unroll
        for (int q = 0; q < 8; ++q) {
            v4f f = *(const v4f*)&HL[i * 32 + 4 * q];
            v2f lo = {f.x, f.y}, hi = {f.z, f.w};
            acc += lo * t2[(2 * q) ^ tw] + hi * t2[(2 * q + 1) ^ tw];
        }
        float wi = acc.x + acc.y;
        if (i & 1) v[i >> 1].y = wi; else v[i >> 1].x = wi;
    }

    jacobi_fg(v, col, SW1);

    float* outp = w1out + gm * 1024 + col;
    #pragma unroll
    for (int j = 0; j < 16; ++j) {
        outp[(2 * j) * 32]     = v[j].x;
        outp[(2 * j + 1) * 32] = v[j].y;
    }
}

// ---------------------------------------------------------------------------
// K3b: GT += mean over matrices of W*diag(log(lam)/lam^2)*W^T  (reads W1).
// ---------------------------------------------------------------------------
__global__ __launch_bounds__(256, 4) void k_gt(const float* __restrict__ w1,
                                               float* __restrict__ ws) {
    __shared__ float WL[8 * 1024];   // pair-swizzled W tiles
    __shared__ float ACC[1024];
    const int tid = threadIdx.x;
    for (int e = tid; e < 1024; e += 256) ACC[e] = 0.f;
    const size_t gbase = (size_t)blockIdx.x * 8192;
    for (int e2 = tid; e2 < 4096; e2 += 256) {
        int mat = e2 >> 9, rp = e2 & 511, r = rp >> 4, p = rp & 15;
        v2f val = *(const v2f*)&w1[gbase + mat * 1024 + r * 32 + 2 * p];
        *(v2f*)&WL[mat * 1024 + r * 32 + 2 * (p ^ (r & 15))] = val;
    }
    __syncthreads();

    const int lane = tid & 63;
    const int base = lane & 32;
    const int col  = lane & 31;
    const int matl = (tid >> 6) * 2 + (lane >> 5);
    float* Wm = WL + matl * 1024;
    const int cm = col & 15, cbase = col * 32;

    float dn = 0.f;
    #pragma unroll
    for (int r = 0; r < 32; ++r) {
        float x = Wm[r * 32 + 2 * ((col >> 1) ^ (r & 15)) + (col & 1)];
        dn = __builtin_fmaf(x, x, dn);
    }
    const float g = 0.5f * logf(dn) * __builtin_amdgcn_rcpf(dn);

    v2f gr2[16];
    #pragma unroll
    for (int p = 0; p < 16; ++p) {
        v2f wr = *(const v2f*)&Wm[cbase + 2 * (p ^ cm)];
        v2f g2;
        g2.x = __shfl(g, base | (2 * p), 64);
        g2.y = __shfl(g, base | (2 * p + 1), 64);
        gr2[p] = g2 * wr;
    }
    const float invN = 1.0f / (float)NMAT;
    #pragma unroll
    for (int i = 0; i < 32; ++i) {
        v2f acc = {0.f, 0.f};
        const int tw = i & 15;
        #pragma unroll
        for (int q = 0; q < 8; ++q) {
            v4f f = *(const v4f*)&Wm[i * 32 + 4 * q];
            v2f lo = {f.x, f.y}, hi = {f.z, f.w};
            acc += lo * gr2[(2 * q) ^ tw] + hi * gr2[(2 * q + 1) ^ tw];
        }
        atomicAdd(&ACC[i * 32 + col], (acc.x + acc.y) * invN);
    }
    __syncthreads();
    for (int e = tid; e < 1024; e += 256) atomicAdd(ws + WS_GT + e, ACC[e]);
}

// ---------------------------------------------------------------------------
// K4: E = exp(GT); Gn = Gs E Gs; Gh = Gn^{-1/2}; K = Gh*Gs -> ws[WS_K].
// Single wave; register Jacobi. GT handled via SPD shift (sign-safe exp).
// ---------------------------------------------------------------------------
__global__ __launch_bounds__(64) void k_karcher(float* __restrict__ ws) {
    __shared__ float LA[32 * SP];
    __shared__ float LB[32 * SP];
    const int lane = threadIdx.x;
    const int col  = lane & 31;
    const int base = lane & 32;

    for (int e = lane; e < 1024; e += 64)
        LB[(e >> 5) * SP + (e & 31)] = ws[WS_GS + e];   // Gs rows
    v2f gsc[16];
    #pragma unroll
    for (int j = 0; j < 16; ++j) {
        gsc[j].x = ws[WS_GS + (2 * j) * 32 + col];
        gsc[j].y = ws[WS_GS + (2 * j + 1) * 32 + col];
    }
    v2f w[16];
    #pragma unroll
    for (int j = 0; j < 16; ++j) {
        w[j].x = ws[WS_GT + (2 * j) * 32 + col];
        w[j].y = ws[WS_GT + (2 * j + 1) * 32 + col];
    }
    // Frobenius-based SPD shift (GT may be indefinite; one-sided Jacobi on
    // GT^2 loses signs and +/- pairs degenerate -> shift makes all positive)
    v2f cn2 = {0.f, 0.f};
    #pragma unroll
    for (int j = 0; j < 16; ++j) cn2 += w[j] * w[j];
    float fro2 = cn2.x + cn2.y;
    #pragma unroll
    for (int m = 16; m >= 1; m >>= 1) fro2 += __shfl_xor(fro2, m, 64);
    const float shift = __builtin_amdgcn_sqrtf(fro2) + 0.01f;
    #pragma unroll
    for (int j = 0; j < 16; ++j) {
        w[j].x += (2 * j     == col) ? shift : 0.f;
        w[j].y += (2 * j + 1 == col) ? shift : 0.f;
    }
    const float dn = jacobi_fg(w, col, SW_SINGLE);
    put_col(LA, w, col);
    __syncthreads();
    const float lam = __builtin_amdgcn_sqrtf(dn) - shift;   // signed eig of GT
    const float ce  = expf(lam) * __builtin_amdgcn_rcpf(dn);
    v2f ec[16];
    recon_col(LA, ce, col, base, ec);        // E = exp(GT) column
    __syncthreads();
    put_col(LA, ec, col);                    // LA <- E
    __syncthreads();
    v2f u[16], gn[16];
    colmm(LA, gsc, u);                       // u = E * gs_col
    colmm(LB, u, gn);                        // Gn col = Gs * u
    const float dn2 = jacobi_fg(gn, col, SW_SINGLE);
    __syncthreads();
    put_col(LA, gn, col);                    // LA <- W(Gn)
    __syncthreads();
    const float lam2 = __builtin_amdgcn_sqrtf(dn2);
    const float ch   = __builtin_amdgcn_rsqf(lam2) * __builtin_amdgcn_rcpf(dn2);
    v2f gh[16];
    recon_col(LA, ch, col, base, gh);        // Gh = Gn^{-1/2} column
    __syncthreads();
    put_col(LA, gh, col);                    // LA <- Gh
    __syncthreads();
    v2f kc[16];
    colmm(LA, gsc, kc);                      // K col = Gh * gs_col
    #pragma unroll
    for (int j = 0; j < 16; ++j) {
        ws[WS_K + (2 * j) * 32 + col]     = kc[j].x;
        ws[WS_K + (2 * j + 1) * 32 + col] = kc[j].y;
    }
}

// ---------------------------------------------------------------------------
// K5 (pass 2, warm): F = K * W1 * diag(lam1^{-1/2}); 3-sweep Jacobi;
// var += sum(log lam)^2; W2 -> wbuf. lam_k = ||f_k||^2.
// ---------------------------------------------------------------------------
__global__ __launch_bounds__(256, 6) void k_batch_warm(float* __restrict__ wbuf,
                                                       float* __restrict__ ws) {
    __shared__ float KL[1024];
    __shared__ float VARB;
    const int tid = threadIdx.x;
    if (tid == 0) VARB = 0.f;
    for (int e = tid; e < 1024; e += 256) KL[e] = ws[WS_K + e];
    __syncthreads();

    const int lane = tid & 63;
    const int col  = lane & 31;
    const int matl = (tid >> 6) * 2 + (lane >> 5);
    const size_t gm = (size_t)blockIdx.x * 8 + matl;
    float* wp = wbuf + gm * 1024 + col;

    float w1[32];
    #pragma unroll
    for (int i = 0; i < 32; ++i) w1[i] = wp[i * 32];
    float nn = 0.f;
    #pragma unroll
    for (int i = 0; i < 32; ++i) nn = __builtin_fmaf(w1[i], w1[i], nn);
    const float s = __builtin_amdgcn_rsqf(__builtin_amdgcn_sqrtf(nn));
    v2f w1s[16];
    #pragma unroll
    for (int j = 0; j < 16; ++j) { w1s[j].x = w1[2 * j] * s; w1s[j].y = w1[2 * j + 1] * s; }

    v2f v[16];
    #pragma unroll
    for (int i = 0; i < 32; ++i) {
        v2f acc = {0.f, 0.f};
        #pragma unroll
        for (int q = 0; q < 8; ++q) {
            v4f f = *(const v4f*)&KL[i * 32 + 4 * q];
            v2f lo = {f.x, f.y}, hi = {f.z, f.w};
            acc += lo * w1s[2 * q] + hi * w1s[2 * q + 1];
        }
        float fi = acc.x + acc.y;
        if (i & 1) v[i >> 1].y = fi; else v[i >> 1].x = fi;
    }

    const float dn = jacobi_fg(v, col, SW2);   // = lambda (factor init)
    const float lg = logf(dn);
    float contrib = lg * lg;
    #pragma unroll
    for (int m = 32; m >= 1; m >>= 1) contrib += __shfl_xor(contrib, m, 64);
    if (lane == 0) atomicAdd(&VARB, contrib);

    #pragma unroll
    for (int j = 0; j < 16; ++j) {
        wp[(2 * j) * 32]     = v[j].x;
        wp[(2 * j + 1) * 32] = v[j].y;
    }
    __syncthreads();
    if (tid == 0) atomicAdd(ws + WS_VAR, VARB * (1.0f / (float)NMAT));
}

// ---------------------------------------------------------------------------
// K6: p = sqrt(1/(var+eps)); Y = C * W2 * diag(lam^{(p-1)/2}); out = Y Y^T.
// ---------------------------------------------------------------------------
__global__ __launch_bounds__(256, 4) void k_final(float* __restrict__ out,
                                                  const float* __restrict__ ws) {
    __shared__ float YL[8 * 1024];
    __shared__ float CL[1024];
    const int tid = threadIdx.x;
    for (int e = tid; e < 1024; e += 256) CL[e] = ws[WS_C + e];
    __syncthreads();

    const int lane = tid & 63;
    const int col  = lane & 31;
    const int matl = (tid >> 6) * 2 + (lane >> 5);
    const size_t gm = (size_t)blockIdx.x * 8 + matl;
    float* Ym = YL + matl * 1024;
    const int cm = col & 15, cbase = col * 32;

    const float var = ws[WS_VAR];
    const float p = sqrtf(1.0f / (var + 1e-5f));

    float w[32];
    #pragma unroll
    for (int i = 0; i < 32; ++i) w[i] = out[gm * 1024 + i * 32 + col];
    float d2 = 0.f;
    #pragma unroll
    for (int i = 0; i < 32; ++i) d2 += w[i] * w[i];
    const float dj = exp2f(log2f(d2) * 0.5f * (p - 1.0f));
    v2f wv2[16];
    #pragma unroll
    for (int j = 0; j < 16; ++j) { wv2[j].x = w[2 * j]; wv2[j].y = w[2 * j + 1]; }

    const int cp = col >> 1, cb = col & 1;
    #pragma unroll
    for (int i = 0; i < 32; ++i) {
        v2f acc = {0.f, 0.f};
        #pragma unroll
        for (int j = 0; j < 16; ++j)
            acc += *(const v2f*)&CL[i * 32 + 2 * j] * wv2[j];
        Ym[i * 32 + 2 * (cp ^ (i & 15)) + cb] = (acc.x + acc.y) * dj;
    }
    __syncthreads();

    v2f yr2[16];
    #pragma unroll
    for (int pp = 0; pp < 16; ++pp) yr2[pp] = *(const v2f*)&YL[matl * 1024 + cbase + 2 * (pp ^ cm)];
    #pragma unroll
    for (int i = 0; i < 32; ++i) {
        v2f acc = {0.f, 0.f};
        #pragma unroll
        for (int s2 = 0; s2 < 16; ++s2)
            acc += *(const v2f*)&Ym[i * 32 + 2 * s2] * yr2[s2 ^ (i & 15)];
        out[gm * 1024 + i * 32 + col] = acc.x + acc.y;
    }
}

extern "C" void kernel_launch(void* const* d_in, const int* in_sizes, int n_in,
                              void* d_out, int out_size, void* d_ws, size_t ws_size,
                              hipStream_t stream) {
    const float* X = (const float*)d_in[0];
    const float* R = (const float*)d_in[1];
    const float* B = (const float*)d_in[2];
    float* out = (float*)d_out;
    float* ws  = (float*)d_ws;

    hipMemsetAsync(d_ws, 0, WS_TOTAL * sizeof(float), stream);
    k_mean<<<NMAT / 64, 256, 0, stream>>>(X, ws);
    k_small_prep<<<2, 64, 0, stream>>>(R, B, ws);
    k_batch_log<<<NMAT / 8, 256, 0, stream>>>(X, out, ws);
    k_gt<<<NMAT / 8, 256, 0, stream>>>(out, ws);
    k_karcher<<<1, 64, 0, stream>>>(ws);
    k_batch_warm<<<NMAT / 8, 256, 0, stream>>>(out, ws);
    k_final<<<NMAT / 8, 256, 0, stream>>>(out, ws);
}